// Round 1
// 394.437 us; speedup vs baseline: 1.7544x; 1.7544x over previous
//
#include <hip/hip_runtime.h>

#define Bn  8
#define Cn  256
#define KCn 32
#define Nn  16384   // 128*128

typedef __attribute__((ext_vector_type(8))) short bf16x8;   // 8 bf16 (4 VGPRs)
typedef __attribute__((ext_vector_type(4))) short short4v;  // 4 bf16 (8 B)
typedef __attribute__((ext_vector_type(4))) float f32x4;    // MFMA acc

__device__ __forceinline__ float elup1(float v) {
    // elu(v)+1 : v>0 ? v+1 : exp(v)
    return v > 0.0f ? v + 1.0f : __expf(v);
}
__device__ __forceinline__ short f2bf(float f) {   // fp32 -> bf16 (RNE)
    unsigned u = __float_as_uint(f);
    return (short)((u + 0x7FFFu + ((u >> 16) & 1u)) >> 16);
}

// ---------------------------------------------------------------------------
// Pass 1 (MFMA): per 256-px chunk:
//   GEMM1: D[kf][px] = Wk·X  (K=c, 8 chunks of 32), km=elup1(D+bk) -> kml[kf][px]
//   Z[kf] += sum_px km  (shfl-reduce + atomics)
//   GEMM2: S[c][kf] += X·KM^T (K=px=256, A-frags from global/L3, B from kml)
// A/B frags: A lane l holds A[l&15][8*(l>>4)+j]; B lane l holds B[8*(l>>4)+j][l&15]
// (same k-map both operands -> correctness independent of HW k-order).
// C/D: col = l&15, row = 4*(l>>4)+j  [verified layout].
// grid (64, B), 512 thr (8 waves, each owns 32 px / 32 c).
// ---------------------------------------------------------------------------
__global__ __launch_bounds__(512, 4) void k_km_S(const float* __restrict__ x,
                                                 const float* __restrict__ Wk,
                                                 const float* __restrict__ bk,
                                                 float* __restrict__ S,
                                                 float* __restrict__ Z) {
    __shared__ short xs[256][40];   // x chunk bf16 [px][c32], row 80 B (2-way max)
    __shared__ short wks[32][264];  // Wk bf16 [kf][c], row 528 B (2-way max)
    __shared__ short kml[32][264];  // km bf16 [kf][px]
    __shared__ float bkl[KCn];

    const int t = threadIdx.x;
    const int b = blockIdx.y;
    const int n0 = blockIdx.x * 256;
    const int lane = t & 63, wv = t >> 6;
    const int g = lane >> 4, l15 = lane & 15;
    const int pxw = wv * 32;
    const float* xb = x + (size_t)b * Cn * Nn;

    {   // stage Wk -> bf16 LDS
        const int row = t >> 4, col0 = (t & 15) * 16;
        const float* src = Wk + row * Cn + col0;
        bf16x8 v0, v1;
#pragma unroll
        for (int i = 0; i < 8; ++i) { v0[i] = f2bf(src[i]); v1[i] = f2bf(src[8 + i]); }
        *(bf16x8*)&wks[row][col0] = v0;
        *(bf16x8*)&wks[row][col0 + 8] = v1;
        if (t < KCn) bkl[t] = bk[t];
    }

    // ---- GEMM1: km = Wk · X ----
    f32x4 acc1[2][2] = {};          // [mt=kf-tile][nt=px-tile]
    for (int kc = 0; kc < 8; ++kc) {
        if (kc) __syncthreads();    // protect xs from previous readers
        {   // stage 32 c x 256 px: thread: px=t&255, ch=t>>8 covers 16 c
            const int px = t & 255, ch = t >> 8;
            const float* sp = xb + (size_t)(kc * 32 + ch * 16) * Nn + n0 + px;
            bf16x8 v0, v1;
#pragma unroll
            for (int i = 0; i < 8; ++i) v0[i] = f2bf(sp[(size_t)i * Nn]);
#pragma unroll
            for (int i = 0; i < 8; ++i) v1[i] = f2bf(sp[(size_t)(8 + i) * Nn]);
            *(bf16x8*)&xs[px][ch * 16] = v0;
            *(bf16x8*)&xs[px][ch * 16 + 8] = v1;
        }
        __syncthreads();
        const bf16x8 af0 = *(const bf16x8*)&wks[l15][kc * 32 + g * 8];
        const bf16x8 af1 = *(const bf16x8*)&wks[16 + l15][kc * 32 + g * 8];
        const bf16x8 bf0 = *(const bf16x8*)&xs[pxw + l15][g * 8];
        const bf16x8 bf1 = *(const bf16x8*)&xs[pxw + 16 + l15][g * 8];
        acc1[0][0] = __builtin_amdgcn_mfma_f32_16x16x32_bf16(af0, bf0, acc1[0][0], 0, 0, 0);
        acc1[0][1] = __builtin_amdgcn_mfma_f32_16x16x32_bf16(af0, bf1, acc1[0][1], 0, 0, 0);
        acc1[1][0] = __builtin_amdgcn_mfma_f32_16x16x32_bf16(af1, bf0, acc1[1][0], 0, 0, 0);
        acc1[1][1] = __builtin_amdgcn_mfma_f32_16x16x32_bf16(af1, bf1, acc1[1][1], 0, 0, 0);
    }

    // ---- epilogue: elu+1 -> kml, Z reduce ----
    {
        float zp[2][4] = {{0.f,0.f,0.f,0.f},{0.f,0.f,0.f,0.f}};
#pragma unroll
        for (int mt = 0; mt < 2; ++mt)
#pragma unroll
            for (int j = 0; j < 4; ++j) {
                const int kf = mt * 16 + g * 4 + j;
                const float bkv = bkl[kf];
#pragma unroll
                for (int nt = 0; nt < 2; ++nt) {
                    const float v = elup1(acc1[mt][nt][j] + bkv);
                    zp[mt][j] += v;
                    kml[kf][pxw + nt * 16 + l15] = f2bf(v);
                }
            }
#pragma unroll
        for (int mt = 0; mt < 2; ++mt)
#pragma unroll
            for (int j = 0; j < 4; ++j) {
                float s = zp[mt][j];
                s += __shfl_xor(s, 1); s += __shfl_xor(s, 2);
                s += __shfl_xor(s, 4); s += __shfl_xor(s, 8);
                if (l15 == 0) atomicAdd(&Z[b * KCn + mt * 16 + g * 4 + j], s);
            }
    }
    __syncthreads();   // kml visible to all waves

    // ---- GEMM2: S[c][kf] += X · KM^T  (wave owns 32 c) ----
    f32x4 acc2[2][2] = {};          // [mt=c-tile][nt=kf-tile]
    const int crow = wv * 32;
    for (int ks = 0; ks < 8; ++ks) {
        bf16x8 a2[2];
#pragma unroll
        for (int mt = 0; mt < 2; ++mt) {
            const float* ap = xb + (size_t)(crow + mt * 16 + l15) * Nn + n0 + ks * 32 + g * 8;
            const float4 f0 = *(const float4*)ap;
            const float4 f1 = *(const float4*)(ap + 4);
            bf16x8 v;
            v[0] = f2bf(f0.x); v[1] = f2bf(f0.y); v[2] = f2bf(f0.z); v[3] = f2bf(f0.w);
            v[4] = f2bf(f1.x); v[5] = f2bf(f1.y); v[6] = f2bf(f1.z); v[7] = f2bf(f1.w);
            a2[mt] = v;
        }
        const bf16x8 b20 = *(const bf16x8*)&kml[l15][ks * 32 + g * 8];
        const bf16x8 b21 = *(const bf16x8*)&kml[16 + l15][ks * 32 + g * 8];
        acc2[0][0] = __builtin_amdgcn_mfma_f32_16x16x32_bf16(a2[0], b20, acc2[0][0], 0, 0, 0);
        acc2[0][1] = __builtin_amdgcn_mfma_f32_16x16x32_bf16(a2[0], b21, acc2[0][1], 0, 0, 0);
        acc2[1][0] = __builtin_amdgcn_mfma_f32_16x16x32_bf16(a2[1], b20, acc2[1][0], 0, 0, 0);
        acc2[1][1] = __builtin_amdgcn_mfma_f32_16x16x32_bf16(a2[1], b21, acc2[1][1], 0, 0, 0);
    }
    float* Sb = S + (size_t)b * Cn * KCn;   // S layout [b][c][kf]
#pragma unroll
    for (int mt = 0; mt < 2; ++mt)
#pragma unroll
        for (int nt = 0; nt < 2; ++nt)
#pragma unroll
            for (int j = 0; j < 4; ++j)
                atomicAdd(&Sb[(crow + mt * 16 + g * 4 + j) * KCn + nt * 16 + l15],
                          acc2[mt][nt][j]);
}

// ---------------------------------------------------------------------------
// Pass 2 (tiny): KVT[b][vc][kf] = bv[vc]*Z[kf] + sum_c Wv[vc][c]*S[b][c][kf]
// stored bf16, [vc][kf] layout (A-operand-ready for pass 3).
// grid (8 vc-chunks, B), 256 thr: thread = (vc, 4 kf).
// ---------------------------------------------------------------------------
__global__ __launch_bounds__(256) void k_kv(const float* __restrict__ Wv,
                                            const float* __restrict__ bv,
                                            const float* __restrict__ S,
                                            const float* __restrict__ Z,
                                            unsigned short* __restrict__ KVT) {
    __shared__ float Sl[Cn][KCn];   // 32 KB
    __shared__ float zl[KCn];
    const int t = threadIdx.x;
    const int b = blockIdx.y;
    const int vc0 = blockIdx.x * 32;
    const float* Sb = S + (size_t)b * Cn * KCn;
#pragma unroll
    for (int i = 0; i < 32; ++i) ((float*)Sl)[i * 256 + t] = Sb[i * 256 + t];
    if (t < KCn) zl[t] = Z[b * KCn + t];
    __syncthreads();
    const int vc = vc0 + (t >> 3);
    const int kq = (t & 7) * 4;
    const float bvv = bv[vc];
    f32x4 acc;
#pragma unroll
    for (int i = 0; i < 4; ++i) acc[i] = bvv * zl[kq + i];
    const float* wv = Wv + (size_t)vc * Cn;
#pragma unroll 4
    for (int c = 0; c < Cn; ++c) {
        const float w = wv[c];
        const f32x4 s4 = *(const f32x4*)&Sl[c][kq];
#pragma unroll
        for (int i = 0; i < 4; ++i) acc[i] += w * s4[i];
    }
    unsigned short* kp = KVT + ((size_t)b * Cn + vc) * KCn + kq;
    ushort4 o;
    o.x = (unsigned short)f2bf(acc[0]); o.y = (unsigned short)f2bf(acc[1]);
    o.z = (unsigned short)f2bf(acc[2]); o.w = (unsigned short)f2bf(acc[3]);
    *(ushort4*)kp = o;
}

// ---------------------------------------------------------------------------
// Pass 3 (MFMA): GEMM1 qm = elup1(Wq·X+bq) -> qml[px][kf] (unscaled);
// GEMM2: U[vc][px] = KVT·QM with KVT augmented by row 256 = Z so that
// U-row 256 = qz[px]; epilogue out = (gamma/max(qz,1e-6))*U + x (fp32).
// grid (64, B), 512 thr.
// ---------------------------------------------------------------------------
__global__ __launch_bounds__(512, 4) void k_out(const float* __restrict__ x,
                                                const float* __restrict__ Wq,
                                                const float* __restrict__ bq,
                                                const unsigned short* __restrict__ KVT,
                                                const float* __restrict__ Z,
                                                const float* __restrict__ gamma,
                                                float* __restrict__ out) {
    __shared__ short xs[256][40];    // x chunk bf16 [px][c32]
    __shared__ short wqs[32][264];   // Wq bf16 [kf][c]
    __shared__ short qml[256][40];   // qm bf16 [px][kf]
    __shared__ short kvtl[272][40];  // KV^T bf16 [vc][kf]; row 256 = Z; 257..271 = 0
    __shared__ float bql[KCn];

    const int t = threadIdx.x;
    const int b = blockIdx.y;
    const int n0 = blockIdx.x * 256;
    const int lane = t & 63, wv = t >> 6;
    const int g = lane >> 4, l15 = lane & 15;
    const int pxw = wv * 32;
    const float* xb = x + (size_t)b * Cn * Nn;

    {   // stage Wq, bq, KVT (+Z row, zero pad rows)
        const int row = t >> 4, col0 = (t & 15) * 16;
        const float* src = Wq + row * Cn + col0;
        bf16x8 v0, v1;
#pragma unroll
        for (int i = 0; i < 8; ++i) { v0[i] = f2bf(src[i]); v1[i] = f2bf(src[8 + i]); }
        *(bf16x8*)&wqs[row][col0] = v0;
        *(bf16x8*)&wqs[row][col0 + 8] = v1;
        if (t < KCn) bql[t] = bq[t];
        const int vc = t >> 1, half = t & 1;
        const bf16x8* kvsrc =
            (const bf16x8*)(KVT + (size_t)b * Cn * KCn + vc * KCn + half * 16);
        *(bf16x8*)&kvtl[vc][half * 16]     = kvsrc[0];
        *(bf16x8*)&kvtl[vc][half * 16 + 8] = kvsrc[1];
        if (t < KCn) kvtl[256][t] = f2bf(Z[b * KCn + t]);
        for (int i = t; i < 15 * 40; i += 512) kvtl[257 + i / 40][i % 40] = 0;
    }

    // ---- GEMM1: qm = Wq · X ----
    f32x4 acc1[2][2] = {};
    for (int kc = 0; kc < 8; ++kc) {
        if (kc) __syncthreads();
        {
            const int px = t & 255, ch = t >> 8;
            const float* sp = xb + (size_t)(kc * 32 + ch * 16) * Nn + n0 + px;
            bf16x8 v0, v1;
#pragma unroll
            for (int i = 0; i < 8; ++i) v0[i] = f2bf(sp[(size_t)i * Nn]);
#pragma unroll
            for (int i = 0; i < 8; ++i) v1[i] = f2bf(sp[(size_t)(8 + i) * Nn]);
            *(bf16x8*)&xs[px][ch * 16] = v0;
            *(bf16x8*)&xs[px][ch * 16 + 8] = v1;
        }
        __syncthreads();
        const bf16x8 af0 = *(const bf16x8*)&wqs[l15][kc * 32 + g * 8];
        const bf16x8 af1 = *(const bf16x8*)&wqs[16 + l15][kc * 32 + g * 8];
        const bf16x8 bf0 = *(const bf16x8*)&xs[pxw + l15][g * 8];
        const bf16x8 bf1 = *(const bf16x8*)&xs[pxw + 16 + l15][g * 8];
        acc1[0][0] = __builtin_amdgcn_mfma_f32_16x16x32_bf16(af0, bf0, acc1[0][0], 0, 0, 0);
        acc1[0][1] = __builtin_amdgcn_mfma_f32_16x16x32_bf16(af0, bf1, acc1[0][1], 0, 0, 0);
        acc1[1][0] = __builtin_amdgcn_mfma_f32_16x16x32_bf16(af1, bf0, acc1[1][0], 0, 0, 0);
        acc1[1][1] = __builtin_amdgcn_mfma_f32_16x16x32_bf16(af1, bf1, acc1[1][1], 0, 0, 0);
    }

    // ---- epilogue GEMM1: qm (unscaled) -> qml[px][kf] ----
#pragma unroll
    for (int mt = 0; mt < 2; ++mt)
#pragma unroll
        for (int nt = 0; nt < 2; ++nt) {
            short4v q4;
#pragma unroll
            for (int j = 0; j < 4; ++j)
                q4[j] = f2bf(elup1(acc1[mt][nt][j] + bql[mt * 16 + g * 4 + j]));
            *(short4v*)&qml[pxw + nt * 16 + l15][mt * 16 + g * 4] = q4;
        }
    // wave reads only its own qml rows -> no cross-wave barrier needed here.

    // ---- GEMM2 + epilogue ----
    const bf16x8 qb0 = *(const bf16x8*)&qml[pxw + l15][g * 8];
    const bf16x8 qb1 = *(const bf16x8*)&qml[pxw + 16 + l15][g * 8];
    f32x4 u0 = {}, u1 = {};
    {   // qz via augmented Z row (row 256)
        const bf16x8 az = *(const bf16x8*)&kvtl[256 + l15][g * 8];
        u0 = __builtin_amdgcn_mfma_f32_16x16x32_bf16(az, qb0, u0, 0, 0, 0);
        u1 = __builtin_amdgcn_mfma_f32_16x16x32_bf16(az, qb1, u1, 0, 0, 0);
    }
    const float qz0 = __shfl(u0[0], l15);   // row 256 lives in lanes 0..15, reg 0
    const float qz1 = __shfl(u1[0], l15);
    const float gm = gamma[0];
    const float r0 = gm / fmaxf(qz0, 1e-6f);
    const float r1 = gm / fmaxf(qz1, 1e-6f);
    float* ob = out + (size_t)b * Cn * Nn + n0;
    const float* xrb = xb + n0;
    const int p0 = pxw + l15, p1 = pxw + 16 + l15;
#pragma unroll 4
    for (int mt = 0; mt < 16; ++mt) {
        const bf16x8 a = *(const bf16x8*)&kvtl[mt * 16 + l15][g * 8];
        f32x4 c0 = {}, c1 = {};
        c0 = __builtin_amdgcn_mfma_f32_16x16x32_bf16(a, qb0, c0, 0, 0, 0);
        c1 = __builtin_amdgcn_mfma_f32_16x16x32_bf16(a, qb1, c1, 0, 0, 0);
#pragma unroll
        for (int j = 0; j < 4; ++j) {
            const size_t ro = (size_t)(mt * 16 + g * 4 + j) * Nn;
            ob[ro + p0] = c0[j] * r0 + xrb[ro + p0];
            ob[ro + p1] = c1[j] * r1 + xrb[ro + p1];
        }
    }
}

// ---------------------------------------------------------------------------
extern "C" void kernel_launch(void* const* d_in, const int* in_sizes, int n_in,
                              void* d_out, int out_size, void* d_ws, size_t ws_size,
                              hipStream_t stream) {
    const float* x     = (const float*)d_in[0];
    const float* Wq    = (const float*)d_in[1];
    const float* bq    = (const float*)d_in[2];
    const float* Wk    = (const float*)d_in[3];
    const float* bk    = (const float*)d_in[4];
    const float* Wv    = (const float*)d_in[5];
    const float* bv    = (const float*)d_in[6];
    const float* gamma = (const float*)d_in[7];
    float* out = (float*)d_out;

    // workspace: S fp32 [B][C][KC] | Z fp32 [B][KC] | KVT bf16 [B][C][KC]
    float* S = (float*)d_ws;
    float* Z = S + (size_t)Bn * Cn * KCn;
    unsigned short* KVT = (unsigned short*)(Z + (size_t)Bn * KCn);

    hipMemsetAsync(d_ws, 0, ((size_t)Bn * Cn * KCn + Bn * KCn) * sizeof(float), stream);
    k_km_S<<<dim3(64, Bn), 512, 0, stream>>>(x, Wk, bk, S, Z);
    k_kv  <<<dim3(8, Bn), 256, 0, stream>>>(Wv, bv, S, Z, KVT);
    k_out <<<dim3(64, Bn), 512, 0, stream>>>(x, Wq, bq, KVT, Z, gamma, out);
}